// Round 9
// baseline (152.092 us; speedup 1.0000x reference)
//
#include <hip/hip_runtime.h>
#include <math.h>

#pragma clang fp contract(off)

// Problem constants
#define B_   128
#define CI_  16
#define CO_  32
#define H_   32
#define W_   32
#define HO_  30
#define WO_  30
#define P_   900                 // HO*WO
#define CP_  (CO_*P_)            // 28800
#define N_   ((size_t)B_*CP_)    // 3686400 elements per tensor
#define NBLK_CONV (4*30*8)       // conv grid blocks = 960 (stats grouping preserved)
#define WSTRIDE_O 129600         // CI_*P_*9
#define WSTRIDE_C 8100           // P_*9
#define FFC_ (H_*W_)             // 1024  (channel stride in ff)
#define FFB_ (CI_*H_*W_)         // 16384 (batch stride in ff)
#define FFTOT_ (B_*FFB_)         // 2097152 total ff floats

// d_out layout (4*N_ floats): [0,N)=soma, [N,2N)=spike, [2N,3N)=a_new, [3N,4N)=b_new.
// Slot [3N,4N) temporarily holds the f32 conv value; LIF reads it before
// overwriting with b_new.

// async global->LDS. LDS dest is wave-uniform base + lane*width.
typedef __attribute__((address_space(1))) const unsigned int gas_uint;
typedef __attribute__((address_space(3))) unsigned int las_uint;
__device__ __forceinline__ void gload_lds4(const float* g, float* l) {
    __builtin_amdgcn_global_load_lds((gas_uint*)g, (las_uint*)l, 4, 0, 0);
}
__device__ __forceinline__ void gload_lds16(const float* g, float* l) {
    __builtin_amdgcn_global_load_lds((gas_uint*)g, (las_uint*)l, 16, 0, 0);
}

// ---------------------------------------------------------------------------
// Kernel 1: locally-connected conv. R5 VERBATIM (best measured: 68 us,
// VGPR 108, occupancy grid-limited). LDS-staged via lane-linear
// global_load_lds, static double-buffer literals, __syncthreads, register
// blocking thread = 2o x 2w x 4b. Weight groups padded to 68 floats (272B
// stride): og-lanes on banks 0/8/16/24 (8-way -> ~2-way residual conflict).
// Grid dim3(4,30,8): weight-sharing blocks (same wt,h; 8 zb's; 147KB each)
// have linear-id distance 120 = 0 mod 8 -> SAME XCD L2 (dominant re-fetch
// stream; R6 proved scattering it costs +15MB FETCH and +25 us).
// Per-output accumulation order (c outer, kh, kw; mul then add, no FMA) is
// bitwise identical to the reference. 960-slot f64 stat grouping unchanged.
// NOTE (R4/R6 lessons): no __launch_bounds__ VGPR cap, no pointer rotation,
// no >2-deep pipeline -- all three blew registers/occupancy.
// ---------------------------------------------------------------------------
__global__ __launch_bounds__(256) void conv_kernel(
    const float* __restrict__ ff, const float* __restrict__ weight,
    const float* __restrict__ conv_bias, float* __restrict__ outf,
    double* __restrict__ part_sum, double* __restrict__ part_sumsq)
{
#pragma clang fp contract(off)
    const int tid = threadIdx.x;
    const int og  = (tid & 3) | ((tid >> 6) << 2);   // 0..15
    const int wg2 = (tid >> 2) & 3;                  // 0..3
    const int bg  = (tid >> 4) & 3;                  // 0..3
    const int wave = tid >> 6;
    const int wt = blockIdx.x;          // 0..3
    const int h  = blockIdx.y;          // 0..29
    const int b0 = blockIdx.z * 16;     // 16 batches per block
    const int w0 = wt * 8 + wg2 * 2;
    const bool val = !(wt == 3 && wg2 == 3);
    const int wwave = tid & ~63;        // wave-uniform lane-0 tid

    __shared__ float wgl[2][2432];      // [buf][o*68 + w*8 + k] + k8 plane at 2176
    __shared__ float ffs[2][576];       // [buf][bb*36 + r*12 + cc]

    // ---- c-independent staging offsets (all in-bounds by construction) ----
    int wq_off[8];
#pragma unroll
    for (int q = 0; q < 8; ++q) {
        int s = q * 256 + tid;
        int o = s >> 6, w = (s >> 3) & 7, k = s & 7;
        int colc = wt * 8 + w; if (colc > 29) colc = 29;   // edge clamp (garbage -> invalid threads only)
        wq_off[q] = o * WSTRIDE_O + (h * WO_ + colc) * 9 + k;
    }
    int w8_off;
    {
        int o = tid >> 3, w = tid & 7;
        int colc = wt * 8 + w; if (colc > 29) colc = 29;
        w8_off = o * WSTRIDE_O + (h * WO_ + colc) * 9 + 8;
    }
    const bool fon = (tid < 144);
    int f_off = 0;
    if (fon) {
        int s0 = 4 * tid;               // 0,4,...,572
        int bb = s0 / 36, rm = s0 % 36, r = rm / 12, cc0 = rm % 12;
        f_off = (b0 + bb) * FFB_ + (h + r) * W_ + wt * 8 + cc0;   // 16B-aligned
    }

    float acc[2][2][4];
#pragma unroll
    for (int oo = 0; oo < 2; ++oo)
#pragma unroll
        for (int ww = 0; ww < 2; ++ww)
#pragma unroll
            for (int j = 0; j < 4; ++j) acc[oo][ww][j] = 0.f;

    auto stage = [&](int c, int buf) {
        const float* wsrc = weight + c * WSTRIDE_C;
#pragma unroll
        for (int q = 0; q < 8; ++q)
            gload_lds4(wsrc + wq_off[q], &wgl[buf][(q * 4 + wave) * 68]);
        gload_lds4(wsrc + w8_off, &wgl[buf][2176 + (wave << 6)]);
        if (fon) {
            int g = f_off + c * FFC_;
            if (g > FFTOT_ - 4) g = FFTOT_ - 4;   // corner clamp (garbage slots only)
            gload_lds16(ff + g, &ffs[buf][4 * wwave]);
        }
    };

    const int o0 = og * 2;
    auto compute_c = [&](int buf) {
        float wk[2][2][9];
#pragma unroll
        for (int oo = 0; oo < 2; ++oo)
#pragma unroll
            for (int ww = 0; ww < 2; ++ww) {
                const int o = o0 + oo, w = wg2 * 2 + ww;
                const float* wp = &wgl[buf][o * 68 + w * 8];      // 272B group stride, 16B-aligned
                const float4 a = *reinterpret_cast<const float4*>(wp);
                const float4 b = *reinterpret_cast<const float4*>(wp + 4);
                wk[oo][ww][0] = a.x; wk[oo][ww][1] = a.y; wk[oo][ww][2] = a.z; wk[oo][ww][3] = a.w;
                wk[oo][ww][4] = b.x; wk[oo][ww][5] = b.y; wk[oo][ww][6] = b.z; wk[oo][ww][7] = b.w;
                wk[oo][ww][8] = wgl[buf][2176 + o * 8 + w];
            }
#pragma unroll
        for (int j = 0; j < 4; ++j) {
            const int bb = bg * 4 + j;
            float fr[3][4];
#pragma unroll
            for (int r = 0; r < 3; ++r) {
                const float2 u = *reinterpret_cast<const float2*>(&ffs[buf][bb * 36 + r * 12 + wg2 * 2]);
                const float2 v = *reinterpret_cast<const float2*>(&ffs[buf][bb * 36 + r * 12 + wg2 * 2 + 2]);
                fr[r][0] = u.x; fr[r][1] = u.y; fr[r][2] = v.x; fr[r][3] = v.y;
            }
#pragma unroll
            for (int oo = 0; oo < 2; ++oo)
#pragma unroll
                for (int ww = 0; ww < 2; ++ww) {
                    float a = acc[oo][ww][j];
#pragma unroll
                    for (int kh = 0; kh < 3; ++kh)
#pragma unroll
                        for (int kw = 0; kw < 3; ++kw) {
                            float prod = wk[oo][ww][kh * 3 + kw] * fr[kh][ww + kw];
                            a = a + prod;      // no FMA, (c,kh,kw) order
                        }
                    acc[oo][ww][j] = a;
                }
        }
    };

    stage(0, 0);
    __syncthreads();
    for (int cs = 0; cs < CI_; cs += 2) {
        if (cs + 1 < CI_) stage(cs + 1, 1);   // prefetch overlaps compute
        compute_c(0);
        __syncthreads();
        if (cs + 2 < CI_) stage(cs + 2, 0);
        compute_c(1);
        __syncthreads();
    }

    // epilogue: bias, park conv values, exact f64 per-block per-channel stats
    double s1[2] = {0.0, 0.0}, s2[2] = {0.0, 0.0};
    if (val) {
#pragma unroll
        for (int oo = 0; oo < 2; ++oo) {
            const int o = o0 + oo;
            const int pidx = o * P_ + h * WO_ + w0;
            const float2 bi = *reinterpret_cast<const float2*>(conv_bias + pidx);
#pragma unroll
            for (int j = 0; j < 4; ++j) {
                const int b = b0 + bg * 4 + j;
                const size_t n = (size_t)b * CP_ + (size_t)pidx;
                float v0 = acc[oo][0][j] + bi.x;     // f32, same as ref
                float v1 = acc[oo][1][j] + bi.y;
                *reinterpret_cast<float2*>(outf + 3 * N_ + n) = make_float2(v0, v1);
                double d0 = (double)v0, d1 = (double)v1;
                s1[oo] += d0; s2[oo] += d0 * d0;
                s1[oo] += d1; s2[oo] += d1 * d1;
            }
        }
    }
    // deterministic reduce over the 16 lanes (stride 4) sharing og
#pragma unroll
    for (int d = 4; d < 64; d <<= 1) {
#pragma unroll
        for (int oo = 0; oo < 2; ++oo) {
            s1[oo] += __shfl_xor(s1[oo], d);
            s2[oo] += __shfl_xor(s2[oo], d);
        }
    }
    if ((tid & 60) == 0) {               // wg2==0 && bg==0
        int blk = (blockIdx.z * 30 + blockIdx.y) * 4 + blockIdx.x;   // 0..959
#pragma unroll
        for (int oo = 0; oo < 2; ++oo) {
            part_sum  [blk * CO_ + o0 + oo] = s1[oo];
            part_sumsq[blk * CO_ + o0 + oo] = s2[oo];
        }
    }
}

// ---------------------------------------------------------------------------
// Kernel 2: BN finalize — deterministic f64 reduction of partials, then
// f32 mean / inv_std per channel. UNCHANGED.
// ---------------------------------------------------------------------------
__global__ __launch_bounds__(256) void bn_finalize(
    const double* __restrict__ part_sum, const double* __restrict__ part_sumsq,
    float* __restrict__ Mb)
{
#pragma clang fp contract(off)
    const int o = blockIdx.x;
    const int tid = threadIdx.x;
    double s1 = 0.0, s2 = 0.0;
    for (int i = tid; i < NBLK_CONV; i += 256) {
        s1 += part_sum[i * CO_ + o];
        s2 += part_sumsq[i * CO_ + o];
    }
    __shared__ double r1[256], r2[256];
    r1[tid] = s1; r2[tid] = s2;
    __syncthreads();
    for (int s = 128; s > 0; s >>= 1) {
        if (tid < s) { r1[tid] += r1[tid + s]; r2[tid] += r2[tid + s]; }
        __syncthreads();
    }
    if (tid == 0) {
        const double cnt = (double)(B_ * (size_t)P_);
        double mean = r1[0] / cnt;
        float meanf = (float)mean;
        double md = (double)meanf;
        double var = r2[0] / cnt - 2.0 * md * (r1[0] / cnt) + md * md;
        float varf = (float)var;
        float invf = 1.0f / sqrtf(varf + 1e-5f);
        Mb[o]       = meanf;
        Mb[CO_ + o] = invf;
    }
}

// ---------------------------------------------------------------------------
// Kernel 3: fused recurrent-bmm + LIF. R7 structure VERBATIM (LDS spike tile,
// parity double-buffer, register prefetch, lgkmcnt(0)-only barrier) with ONE
// change: block geometry 256 thr = 32 i x 8 p (was 1024 = 32 i x 32 p).
// R7/R8 evidence: LDS-sharing beats per-thread global gather (R8: 93 us,
// issue-bound), but 1024-thr blocks gave 1.8 blocks/CU and 16-wave barrier
// convoys (R7: 70 us, occ 35%, VALUBusy 19%). 256-thr blocks: ~7 active
// blocks/CU (28 waves/CU), 4-wave barriers, 1KB tile staged exactly once
// per (pt,b) -> no traffic increase. XCD grouping kept: D&7 = pt&7, so the
// 16 bg-sharers of a local_rec/tau/spk p-slice land on one XCD's L2.
// Grid 1920 = 8 pt8 x 16 bg x 15 ptq (pt = ptq*8+pt8, 113 ptiles, 7 idle).
// Per-output arithmetic identical to R7 => bit-identical outputs.
// ---------------------------------------------------------------------------
__global__ __launch_bounds__(256) void lif_rec_kernel(
    float* __restrict__ outf, const float* __restrict__ local_rec,
    const float* __restrict__ tau_m, const float* __restrict__ tau_adp,
    const float* __restrict__ tau_a, const float* __restrict__ Mb,
    const float* __restrict__ gamma, const float* __restrict__ beta,
    const float* __restrict__ fb, const float* __restrict__ soma_t,
    const float* __restrict__ spk_t, const float* __restrict__ a_curr,
    const float* __restrict__ b_t)
{
#pragma clang fp contract(off)
    const int D    = blockIdx.x;         // 0..1919
    const int pt8  = D & 7;
    const int rest = D >> 3;
    const int bg   = rest & 15;
    const int ptq  = rest >> 4;          // 0..14
    const int pt   = ptq * 8 + pt8;      // 0..119
    if (pt >= 113) return;               // 113 p-tiles of 8 cover P_=900

    const int tid = threadIdx.x;
    const int pp  = tid & 7;
    const int i   = tid >> 3;            // channel 0..31
    const int p   = pt * 8 + pp;
    const bool pv = (p < P_);
    const int b0  = bg * 8;

    float L[32];
    float meanf = 0.f, invf = 0.f, gm = 0.f, be = 0.f;
    float al = 0.f, rh = 0.f, et = 0.f;
    int rem = 0;
    if (pv) {
        const float4* lp = reinterpret_cast<const float4*>(local_rec + (size_t)p * (CO_ * CO_) + i * CO_);
#pragma unroll
        for (int q = 0; q < 8; ++q) {
            float4 v = lp[q];
            L[4 * q] = v.x; L[4 * q + 1] = v.y; L[4 * q + 2] = v.z; L[4 * q + 3] = v.w;
        }
        rem = i * P_ + p;
        meanf = Mb[i]; invf = Mb[CO_ + i];
        gm = gamma[i]; be = beta[i];
        // identical f32 ops to the original tau table: f32 divide then f32 exp
        al = expf(-0.5f / tau_m[rem]);
        rh = expf(-0.5f / tau_adp[rem]);
        et = expf(-0.5f / tau_a[rem]);
    }

    __shared__ float sp[2][CO_][8];

    // prologue: iteration-0 operands into registers
    size_t n = (size_t)b0 * CP_ + (size_t)rem;
    float sk_c = 0.f, cv_c = 0.f, bt_c = 0.f, ac_c = 0.f, fb_c = 0.f, so_c = 0.f;
    if (pv) {
        sk_c = spk_t[n]; cv_c = outf[3 * N_ + n]; bt_c = b_t[n];
        ac_c = a_curr[n]; fb_c = fb[n]; so_c = soma_t[n];
    }

#pragma unroll
    for (int bb = 0; bb < 8; ++bb) {
        const int cb = bb & 1;
        if (pv) sp[cb][i][pp] = sk_c;
        // prefetch next iteration BEFORE the barrier (stays in flight: the
        // raw barrier below drains lgkmcnt only, not vmcnt)
        float sk_n = 0.f, cv_n = 0.f, bt_n = 0.f, ac_n = 0.f, fb_n = 0.f, so_n = 0.f;
        if (bb + 1 < 8 && pv) {
            const size_t nn = n + (size_t)CP_;
            sk_n = spk_t[nn]; cv_n = outf[3 * N_ + nn]; bt_n = b_t[nn];
            ac_n = a_curr[nn]; fb_n = fb[nn]; so_n = soma_t[nn];
        }
        asm volatile("s_waitcnt lgkmcnt(0)\n\ts_barrier" ::: "memory");
        if (pv) {
            // rec: sequential f32 dot over j, no FMA (np einsum order)
            float rec = 0.f;
#pragma unroll
            for (int j = 0; j < CO_; ++j) {
                float prod = L[j] * sp[cb][j][pp];
                rec = rec + prod;
            }

            // BN exactly as reference
            float t  = cv_c - meanf;
            float x  = t * invf;
            float xg = x * gm;
            float cx = xg + be;
            cx = cx + rec;

            // b_new = rho*b_t + (1-rho)*spk
            float rb  = rh * bt_c;
            float omr = 1.0f - rh;
            float os  = omr * sk_c;
            float bn  = rb + os;
            // new_thre = 0.1 + 1.8*b_new
            float tb = 1.8f * bn;
            float th = 0.1f + tb;
            // a_new = eta*a_curr + fb
            float ea = et * ac_c;
            float an = ea + fb_c;
            // sigmoid
            float sg = 1.0f / (1.0f + expf(-an));
            // soma_new = alpha*soma + (sig-0.5) + cx - thre*spk  (left-to-right)
            float as = al * so_c;
            float s5 = sg - 0.5f;
            float u1 = as + s5;
            float u2 = u1 + cx;
            float ts = th * sk_c;
            float sn = u2 - ts;

            outf[n]          = sn;
            outf[N_ + n]     = ((sn - th) > 0.0f) ? 1.f : 0.f;
            outf[2 * N_ + n] = an;
            outf[3 * N_ + n] = bn;                                // overwrites conv
        }
        sk_c = sk_n; cv_c = cv_n; bt_c = bt_n; ac_c = ac_n; fb_c = fb_n; so_c = so_n;
        n += (size_t)CP_;
    }
}

extern "C" void kernel_launch(void* const* d_in, const int* in_sizes, int n_in,
                              void* d_out, int out_size, void* d_ws, size_t ws_size,
                              hipStream_t stream)
{
    const float* ff        = (const float*)d_in[0];
    const float* fb        = (const float*)d_in[1];
    const float* soma_t    = (const float*)d_in[2];
    const float* spk_t     = (const float*)d_in[3];
    const float* a_curr    = (const float*)d_in[4];
    const float* b_t       = (const float*)d_in[5];
    const float* weight    = (const float*)d_in[6];
    const float* conv_bias = (const float*)d_in[7];
    const float* local_rec = (const float*)d_in[8];
    const float* gamma     = (const float*)d_in[9];
    const float* beta      = (const float*)d_in[10];
    const float* tau_m     = (const float*)d_in[11];
    const float* tau_adp   = (const float*)d_in[12];
    const float* tau_a     = (const float*)d_in[13];

    // ws: f64 partials then Mb (~0.5 MB total)
    double* part_sum = (double*)d_ws;                       // NBLK_CONV*CO_
    double* part_sq  = part_sum + (size_t)NBLK_CONV * CO_;  // NBLK_CONV*CO_
    float*  Mb       = (float*)(part_sq + (size_t)NBLK_CONV * CO_);  // 64

    float* outf = (float*)d_out;

    conv_kernel<<<dim3(4, 30, 8), 256, 0, stream>>>(
        ff, weight, conv_bias, outf, part_sum, part_sq);
    bn_finalize<<<dim3(CO_), 256, 0, stream>>>(part_sum, part_sq, Mb);
    lif_rec_kernel<<<dim3(1920), 256, 0, stream>>>(
        outf, local_rec, tau_m, tau_adp, tau_a, Mb, gamma, beta,
        fb, soma_t, spk_t, a_curr, b_t);
}

// Round 10
// 138.195 us; speedup vs baseline: 1.1006x; 1.1006x over previous
//
#include <hip/hip_runtime.h>
#include <math.h>

#pragma clang fp contract(off)

// Problem constants
#define B_   128
#define CI_  16
#define CO_  32
#define H_   32
#define W_   32
#define HO_  30
#define WO_  30
#define P_   900                 // HO*WO
#define CP_  (CO_*P_)            // 28800
#define N_   ((size_t)B_*CP_)    // 3686400 elements per tensor
#define NBLK_CONV (4*30*16)      // conv grid blocks = 1920 (8 batches per block)
#define WSTRIDE_O 129600         // CI_*P_*9
#define WSTRIDE_C 8100           // P_*9
#define FFC_ (H_*W_)             // 1024  (channel stride in ff)
#define FFB_ (CI_*H_*W_)         // 16384 (batch stride in ff)
#define FFTOT_ (B_*FFB_)         // 2097152 total ff floats

// d_out layout (4*N_ floats): [0,N)=soma, [N,2N)=spike, [2N,3N)=a_new, [3N,4N)=b_new.
// Slot [3N,4N) temporarily holds the f32 conv value; LIF reads it before
// overwriting with b_new. Slot [N,2N) (spike) is DEAD until lif runs, so the
// f64 BN partials (1920*32*2 = 983KB) are parked there (8B-aligned: N_*4 is
// divisible by 8) -- removes any d_ws-size dependence. Mb (64 f32) is in ws.

// async global->LDS. LDS dest is wave-uniform base + lane*width.
typedef __attribute__((address_space(1))) const unsigned int gas_uint;
typedef __attribute__((address_space(3))) unsigned int las_uint;
__device__ __forceinline__ void gload_lds4(const float* g, float* l) {
    __builtin_amdgcn_global_load_lds((gas_uint*)g, (las_uint*)l, 4, 0, 0);
}
__device__ __forceinline__ void gload_lds16(const float* g, float* l) {
    __builtin_amdgcn_global_load_lds((gas_uint*)g, (las_uint*)l, 16, 0, 0);
}

// ---------------------------------------------------------------------------
// Kernel 1: locally-connected conv. R5 mechanism VERBATIM (lane-linear
// global_load_lds staging, static double-buffer literals, __syncthreads,
// 68-float padded weight groups -> ~2-way residual bank conflict), with the
// occupancy fix R9's ledger points at: 8 batches/block, grid dim3(4,30,16)
// = 1920 blocks (~7 blocks/CU; LDS 21.8KB allows 7). Thread = 2o x 2w x 2b
// (acc 8 regs, VGPR ~95). Weight-sharing blocks (same wt,h; 16 z's) are 120
// apart in linear id = 0 mod 8 -> SAME XCD L2 (R6-proven requirement).
// Per-output accumulation order (c outer, kh, kw; mul then add, no FMA) is
// bitwise identical. Stats: 1920 deterministic f64 slots (vs 960) -- final
// mean/var differ only in f64 summation rounding (<< 1 ulp of f32 mean).
// NOTE (R4/R6 lessons): no __launch_bounds__ VGPR cap, no pointer rotation,
// no >2-deep pipeline.
// ---------------------------------------------------------------------------
__global__ __launch_bounds__(256) void conv_kernel(
    const float* __restrict__ ff, const float* __restrict__ weight,
    const float* __restrict__ conv_bias, float* __restrict__ outf,
    double* __restrict__ part_sum, double* __restrict__ part_sumsq)
{
#pragma clang fp contract(off)
    const int tid = threadIdx.x;
    const int og  = (tid & 3) | ((tid >> 6) << 2);   // 0..15
    const int wg2 = (tid >> 2) & 3;                  // 0..3
    const int bg  = (tid >> 4) & 3;                  // 0..3
    const int wave = tid >> 6;
    const int wt = blockIdx.x;          // 0..3
    const int h  = blockIdx.y;          // 0..29
    const int b0 = blockIdx.z * 8;      // 8 batches per block
    const int w0 = wt * 8 + wg2 * 2;
    const bool val = !(wt == 3 && wg2 == 3);
    const int wwave = tid & ~63;        // wave-uniform lane-0 tid

    __shared__ float wgl[2][2432];      // [buf][o*68 + w*8 + k] + k8 plane at 2176
    __shared__ float ffs[2][288];       // [buf][bb*36 + r*12 + cc], bb 0..7

    // ---- c-independent staging offsets (all in-bounds by construction) ----
    int wq_off[8];
#pragma unroll
    for (int q = 0; q < 8; ++q) {
        int s = q * 256 + tid;
        int o = s >> 6, w = (s >> 3) & 7, k = s & 7;
        int colc = wt * 8 + w; if (colc > 29) colc = 29;   // edge clamp (garbage -> invalid threads only)
        wq_off[q] = o * WSTRIDE_O + (h * WO_ + colc) * 9 + k;
    }
    int w8_off;
    {
        int o = tid >> 3, w = tid & 7;
        int colc = wt * 8 + w; if (colc > 29) colc = 29;
        w8_off = o * WSTRIDE_O + (h * WO_ + colc) * 9 + 8;
    }
    const bool fon = (tid < 72);        // 72 lanes x 16B = 288 floats
    int f_off = 0;
    if (fon) {
        int s0 = 4 * tid;               // 0,4,...,284
        int bb = s0 / 36, rm = s0 % 36, r = rm / 12, cc0 = rm % 12;
        f_off = (b0 + bb) * FFB_ + (h + r) * W_ + wt * 8 + cc0;   // 16B-aligned
    }

    float acc[2][2][2];
#pragma unroll
    for (int oo = 0; oo < 2; ++oo)
#pragma unroll
        for (int ww = 0; ww < 2; ++ww)
#pragma unroll
            for (int j = 0; j < 2; ++j) acc[oo][ww][j] = 0.f;

    auto stage = [&](int c, int buf) {
        const float* wsrc = weight + c * WSTRIDE_C;
#pragma unroll
        for (int q = 0; q < 8; ++q)
            gload_lds4(wsrc + wq_off[q], &wgl[buf][(q * 4 + wave) * 68]);
        gload_lds4(wsrc + w8_off, &wgl[buf][2176 + (wave << 6)]);
        if (fon) {
            int g = f_off + c * FFC_;
            if (g > FFTOT_ - 4) g = FFTOT_ - 4;   // corner clamp (garbage slots only)
            gload_lds16(ff + g, &ffs[buf][4 * wwave]);
        }
    };

    const int o0 = og * 2;
    auto compute_c = [&](int buf) {
        float wk[2][2][9];
#pragma unroll
        for (int oo = 0; oo < 2; ++oo)
#pragma unroll
            for (int ww = 0; ww < 2; ++ww) {
                const int o = o0 + oo, w = wg2 * 2 + ww;
                const float* wp = &wgl[buf][o * 68 + w * 8];      // 272B group stride, 16B-aligned
                const float4 a = *reinterpret_cast<const float4*>(wp);
                const float4 b = *reinterpret_cast<const float4*>(wp + 4);
                wk[oo][ww][0] = a.x; wk[oo][ww][1] = a.y; wk[oo][ww][2] = a.z; wk[oo][ww][3] = a.w;
                wk[oo][ww][4] = b.x; wk[oo][ww][5] = b.y; wk[oo][ww][6] = b.z; wk[oo][ww][7] = b.w;
                wk[oo][ww][8] = wgl[buf][2176 + o * 8 + w];
            }
#pragma unroll
        for (int j = 0; j < 2; ++j) {
            const int bb = bg * 2 + j;
            float fr[3][4];
#pragma unroll
            for (int r = 0; r < 3; ++r) {
                const float2 u = *reinterpret_cast<const float2*>(&ffs[buf][bb * 36 + r * 12 + wg2 * 2]);
                const float2 v = *reinterpret_cast<const float2*>(&ffs[buf][bb * 36 + r * 12 + wg2 * 2 + 2]);
                fr[r][0] = u.x; fr[r][1] = u.y; fr[r][2] = v.x; fr[r][3] = v.y;
            }
#pragma unroll
            for (int oo = 0; oo < 2; ++oo)
#pragma unroll
                for (int ww = 0; ww < 2; ++ww) {
                    float a = acc[oo][ww][j];
#pragma unroll
                    for (int kh = 0; kh < 3; ++kh)
#pragma unroll
                        for (int kw = 0; kw < 3; ++kw) {
                            float prod = wk[oo][ww][kh * 3 + kw] * fr[kh][ww + kw];
                            a = a + prod;      // no FMA, (c,kh,kw) order
                        }
                    acc[oo][ww][j] = a;
                }
        }
    };

    stage(0, 0);
    __syncthreads();
    for (int cs = 0; cs < CI_; cs += 2) {
        if (cs + 1 < CI_) stage(cs + 1, 1);   // prefetch overlaps compute
        compute_c(0);
        __syncthreads();
        if (cs + 2 < CI_) stage(cs + 2, 0);
        compute_c(1);
        __syncthreads();
    }

    // epilogue: bias, park conv values, exact f64 per-block per-channel stats
    double s1[2] = {0.0, 0.0}, s2[2] = {0.0, 0.0};
    if (val) {
#pragma unroll
        for (int oo = 0; oo < 2; ++oo) {
            const int o = o0 + oo;
            const int pidx = o * P_ + h * WO_ + w0;
            const float2 bi = *reinterpret_cast<const float2*>(conv_bias + pidx);
#pragma unroll
            for (int j = 0; j < 2; ++j) {
                const int b = b0 + bg * 2 + j;
                const size_t n = (size_t)b * CP_ + (size_t)pidx;
                float v0 = acc[oo][0][j] + bi.x;     // f32, same as ref
                float v1 = acc[oo][1][j] + bi.y;
                *reinterpret_cast<float2*>(outf + 3 * N_ + n) = make_float2(v0, v1);
                double d0 = (double)v0, d1 = (double)v1;
                s1[oo] += d0; s2[oo] += d0 * d0;
                s1[oo] += d1; s2[oo] += d1 * d1;
            }
        }
    }
    // deterministic reduce over the 16 lanes (stride 4) sharing og
#pragma unroll
    for (int d = 4; d < 64; d <<= 1) {
#pragma unroll
        for (int oo = 0; oo < 2; ++oo) {
            s1[oo] += __shfl_xor(s1[oo], d);
            s2[oo] += __shfl_xor(s2[oo], d);
        }
    }
    if ((tid & 60) == 0) {               // wg2==0 && bg==0
        int blk = (blockIdx.z * 30 + blockIdx.y) * 4 + blockIdx.x;   // 0..1919
#pragma unroll
        for (int oo = 0; oo < 2; ++oo) {
            part_sum  [blk * CO_ + o0 + oo] = s1[oo];
            part_sumsq[blk * CO_ + o0 + oo] = s2[oo];
        }
    }
}

// ---------------------------------------------------------------------------
// Kernel 2: BN finalize — deterministic f64 reduction of partials (1920
// slots), then f32 mean / inv_std per channel. Same structure as before.
// ---------------------------------------------------------------------------
__global__ __launch_bounds__(256) void bn_finalize(
    const double* __restrict__ part_sum, const double* __restrict__ part_sumsq,
    float* __restrict__ Mb)
{
#pragma clang fp contract(off)
    const int o = blockIdx.x;
    const int tid = threadIdx.x;
    double s1 = 0.0, s2 = 0.0;
    for (int i = tid; i < NBLK_CONV; i += 256) {
        s1 += part_sum[i * CO_ + o];
        s2 += part_sumsq[i * CO_ + o];
    }
    __shared__ double r1[256], r2[256];
    r1[tid] = s1; r2[tid] = s2;
    __syncthreads();
    for (int s = 128; s > 0; s >>= 1) {
        if (tid < s) { r1[tid] += r1[tid + s]; r2[tid] += r2[tid + s]; }
        __syncthreads();
    }
    if (tid == 0) {
        const double cnt = (double)(B_ * (size_t)P_);
        double mean = r1[0] / cnt;
        float meanf = (float)mean;
        double md = (double)meanf;
        double var = r2[0] / cnt - 2.0 * md * (r1[0] / cnt) + md * md;
        float varf = (float)var;
        float invf = 1.0f / sqrtf(varf + 1e-5f);
        Mb[o]       = meanf;
        Mb[CO_ + o] = invf;
    }
}

// ---------------------------------------------------------------------------
// Kernel 3: fused recurrent-bmm + LIF. R7 mechanism VERBATIM (LDS spike
// tile, parity double-buffer, register prefetch, lgkmcnt(0)-only barrier),
// geometry fixed per the R7/R8/R9 ledger: 512 thr = 32 i x 16 p.
//  - p-runs are 16 consecutive (64B/lane-group): keeps coalescing (R9's
//    8-wide p doubled FETCH to 198MB);
//  - 4 blocks/CU (32 waves/CU) vs R7's 1.8: TLP hides latency;
//  - 8-wave barrier convoys vs R7's 16.
// XCD decode: D&7 = pt8, so the 16 bg-sharers of a local_rec/tau/spk
// p-slice land on one XCD's L2 (R6/R7-verified). Grid 1024 = 8 ptq x 16 bg
// x 8 pt8; pt = ptq*8+pt8, 57 active p-tiles.
// Per-output arithmetic identical to R7 => bit-identical outputs.
// ---------------------------------------------------------------------------
__global__ __launch_bounds__(512) void lif_rec_kernel(
    float* __restrict__ outf, const float* __restrict__ local_rec,
    const float* __restrict__ tau_m, const float* __restrict__ tau_adp,
    const float* __restrict__ tau_a, const float* __restrict__ Mb,
    const float* __restrict__ gamma, const float* __restrict__ beta,
    const float* __restrict__ fb, const float* __restrict__ soma_t,
    const float* __restrict__ spk_t, const float* __restrict__ a_curr,
    const float* __restrict__ b_t)
{
#pragma clang fp contract(off)
    const int D    = blockIdx.x;         // 0..1023
    const int pt8  = D & 7;
    const int rest = D >> 3;
    const int bg   = rest & 15;
    const int ptq  = rest >> 4;          // 0..7
    const int pt   = ptq * 8 + pt8;      // 0..63
    if (pt >= 57) return;                // 57 p-tiles of 16 cover P_=900

    const int tid = threadIdx.x;
    const int pp  = tid & 15;
    const int i   = tid >> 4;            // channel 0..31
    const int p   = pt * 16 + pp;
    const bool pv = (p < P_);
    const int b0  = bg * 8;

    float L[32];
    float meanf = 0.f, invf = 0.f, gm = 0.f, be = 0.f;
    float al = 0.f, rh = 0.f, et = 0.f;
    int rem = 0;
    if (pv) {
        const float4* lp = reinterpret_cast<const float4*>(local_rec + (size_t)p * (CO_ * CO_) + i * CO_);
#pragma unroll
        for (int q = 0; q < 8; ++q) {
            float4 v = lp[q];
            L[4 * q] = v.x; L[4 * q + 1] = v.y; L[4 * q + 2] = v.z; L[4 * q + 3] = v.w;
        }
        rem = i * P_ + p;
        meanf = Mb[i]; invf = Mb[CO_ + i];
        gm = gamma[i]; be = beta[i];
        // identical f32 ops to the original tau table: f32 divide then f32 exp
        al = expf(-0.5f / tau_m[rem]);
        rh = expf(-0.5f / tau_adp[rem]);
        et = expf(-0.5f / tau_a[rem]);
    }

    __shared__ float sp[2][CO_][16];

    // prologue: iteration-0 operands into registers
    size_t n = (size_t)b0 * CP_ + (size_t)rem;
    float sk_c = 0.f, cv_c = 0.f, bt_c = 0.f, ac_c = 0.f, fb_c = 0.f, so_c = 0.f;
    if (pv) {
        sk_c = spk_t[n]; cv_c = outf[3 * N_ + n]; bt_c = b_t[n];
        ac_c = a_curr[n]; fb_c = fb[n]; so_c = soma_t[n];
    }

#pragma unroll
    for (int bb = 0; bb < 8; ++bb) {
        const int cb = bb & 1;
        if (pv) sp[cb][i][pp] = sk_c;
        // prefetch next iteration BEFORE the barrier (stays in flight: the
        // raw barrier below drains lgkmcnt only, not vmcnt)
        float sk_n = 0.f, cv_n = 0.f, bt_n = 0.f, ac_n = 0.f, fb_n = 0.f, so_n = 0.f;
        if (bb + 1 < 8 && pv) {
            const size_t nn = n + (size_t)CP_;
            sk_n = spk_t[nn]; cv_n = outf[3 * N_ + nn]; bt_n = b_t[nn];
            ac_n = a_curr[nn]; fb_n = fb[nn]; so_n = soma_t[nn];
        }
        asm volatile("s_waitcnt lgkmcnt(0)\n\ts_barrier" ::: "memory");
        if (pv) {
            // rec: sequential f32 dot over j, no FMA (np einsum order)
            float rec = 0.f;
#pragma unroll
            for (int j = 0; j < CO_; ++j) {
                float prod = L[j] * sp[cb][j][pp];
                rec = rec + prod;
            }

            // BN exactly as reference
            float t  = cv_c - meanf;
            float x  = t * invf;
            float xg = x * gm;
            float cx = xg + be;
            cx = cx + rec;

            // b_new = rho*b_t + (1-rho)*spk
            float rb  = rh * bt_c;
            float omr = 1.0f - rh;
            float os  = omr * sk_c;
            float bn  = rb + os;
            // new_thre = 0.1 + 1.8*b_new
            float tb = 1.8f * bn;
            float th = 0.1f + tb;
            // a_new = eta*a_curr + fb
            float ea = et * ac_c;
            float an = ea + fb_c;
            // sigmoid
            float sg = 1.0f / (1.0f + expf(-an));
            // soma_new = alpha*soma + (sig-0.5) + cx - thre*spk  (left-to-right)
            float as = al * so_c;
            float s5 = sg - 0.5f;
            float u1 = as + s5;
            float u2 = u1 + cx;
            float ts = th * sk_c;
            float sn = u2 - ts;

            outf[n]          = sn;
            outf[N_ + n]     = ((sn - th) > 0.0f) ? 1.f : 0.f;
            outf[2 * N_ + n] = an;
            outf[3 * N_ + n] = bn;                                // overwrites conv
        }
        sk_c = sk_n; cv_c = cv_n; bt_c = bt_n; ac_c = ac_n; fb_c = fb_n; so_c = so_n;
        n += (size_t)CP_;
    }
}

extern "C" void kernel_launch(void* const* d_in, const int* in_sizes, int n_in,
                              void* d_out, int out_size, void* d_ws, size_t ws_size,
                              hipStream_t stream)
{
    const float* ff        = (const float*)d_in[0];
    const float* fb        = (const float*)d_in[1];
    const float* soma_t    = (const float*)d_in[2];
    const float* spk_t     = (const float*)d_in[3];
    const float* a_curr    = (const float*)d_in[4];
    const float* b_t       = (const float*)d_in[5];
    const float* weight    = (const float*)d_in[6];
    const float* conv_bias = (const float*)d_in[7];
    const float* local_rec = (const float*)d_in[8];
    const float* gamma     = (const float*)d_in[9];
    const float* beta      = (const float*)d_in[10];
    const float* tau_m     = (const float*)d_in[11];
    const float* tau_adp   = (const float*)d_in[12];
    const float* tau_a     = (const float*)d_in[13];

    float* outf = (float*)d_out;

    // BN partials live in the dead spike slot [N,2N) of d_out until lif
    // overwrites it (conv -> bn_finalize -> lif are stream-ordered).
    // N_*4 bytes is 8-divisible => f64-aligned.
    double* part_sum = (double*)(outf + N_);                // NBLK_CONV*CO_ f64
    double* part_sq  = part_sum + (size_t)NBLK_CONV * CO_;  // NBLK_CONV*CO_ f64
    float*  Mb       = (float*)d_ws;                        // 64 f32 (tiny)

    conv_kernel<<<dim3(4, 30, 16), 256, 0, stream>>>(
        ff, weight, conv_bias, outf, part_sum, part_sq);
    bn_finalize<<<dim3(CO_), 256, 0, stream>>>(part_sum, part_sq, Mb);
    lif_rec_kernel<<<dim3(1024), 512, 0, stream>>>(
        outf, local_rec, tau_m, tau_adp, tau_a, Mb, gamma, beta,
        fb, soma_t, spk_t, a_curr, b_t);
}

// Round 11
// 110.736 us; speedup vs baseline: 1.3735x; 1.2480x over previous
//
#include <hip/hip_runtime.h>
#include <math.h>

#pragma clang fp contract(off)

// Problem constants
#define B_   128
#define CI_  16
#define CO_  32
#define H_   32
#define W_   32
#define HO_  30
#define WO_  30
#define P_   900                 // HO*WO
#define CP_  (CO_*P_)            // 28800
#define N_   ((size_t)B_*CP_)    // 3686400 elements per tensor
#define NBLK_CONV (4*30*8)       // stat slots = 960 (UNCHANGED -> stats bitwise identical)
#define WSTRIDE_O 129600         // CI_*P_*9
#define WSTRIDE_C 8100           // P_*9
#define FFC_ (H_*W_)             // 1024  (channel stride in ff)
#define FFB_ (CI_*H_*W_)         // 16384 (batch stride in ff)
#define FFTOT_ (B_*FFB_)         // 2097152 total ff floats

// d_out layout (4*N_ floats): [0,N)=soma, [N,2N)=spike, [2N,3N)=a_new, [3N,4N)=b_new.
// Slot [3N,4N) temporarily holds the f32 conv value; LIF reads it before
// overwriting with b_new.

// async global->LDS. LDS dest is wave-uniform base + lane*width.
typedef __attribute__((address_space(1))) const unsigned int gas_uint;
typedef __attribute__((address_space(3))) unsigned int las_uint;
__device__ __forceinline__ void gload_lds4(const float* g, float* l) {
    __builtin_amdgcn_global_load_lds((gas_uint*)g, (las_uint*)l, 4, 0, 0);
}
__device__ __forceinline__ void gload_lds16(const float* g, float* l) {
    __builtin_amdgcn_global_load_lds((gas_uint*)g, (las_uint*)l, 16, 0, 0);
}

// ---------------------------------------------------------------------------
// Kernel 1: locally-connected conv. R5 mechanism VERBATIM, split along O
// (the R10 lesson: per-block cost is dominated by per-o weight staging, so
// block-splitting must cut o, not b). Each block: 16 o x 8 w x 16 b.
// Grid dim3(8,30,8) = 1920 blocks (~7.5/CU; LDS 14.3KB). bx = wt + 4*os.
//  - weight staging per output UNCHANGED (block stages only its 16 o's:
//    4.5KB/channel); ff staging doubled (cheap stream, 2.25KB/channel).
//  - weight-sharing blocks (same bx,y; 8 z's) are 240 apart = 0 mod 8
//    -> SAME XCD L2 (R6-proven requirement).
//  - thread = 1o x 2w x 4b: wk reads halve to 4 b128 + 2 b32 (~2-way
//    conflict as R5); ff reads unchanged; acc 8 regs; VGPR ~80.
//  - vmcnt(0) barrier drain is 5 VMEM/wave (was 9.5) and overlaps across
//    2x the resident blocks.
// Stats: same 960x32 f64 slots; each lane sums the same 8 values in the
// same order, same d=4..32 shuffle tree as R5 -> slot values BITWISE
// identical -> outputs bit-identical to the R7 champion.
// Per-output accumulation order (c outer, kh, kw; mul then add, no FMA).
// NOTE (R4/R6 lessons): no __launch_bounds__ VGPR cap, no pointer rotation,
// no >2-deep pipeline.
// ---------------------------------------------------------------------------
__global__ __launch_bounds__(256) void conv_kernel(
    const float* __restrict__ ff, const float* __restrict__ weight,
    const float* __restrict__ conv_bias, float* __restrict__ outf,
    double* __restrict__ part_sum, double* __restrict__ part_sumsq)
{
#pragma clang fp contract(off)
    const int tid = threadIdx.x;
    const int og  = (tid & 3) | ((tid >> 6) << 2);   // 0..15 (4 per wave)
    const int wg2 = (tid >> 2) & 3;                  // 0..3
    const int bg  = (tid >> 4) & 3;                  // 0..3
    const int wave = tid >> 6;
    const int wt = blockIdx.x & 3;      // 0..3
    const int os = blockIdx.x >> 2;     // 0..1  (o half: os*16 .. os*16+15)
    const int h  = blockIdx.y;          // 0..29
    const int b0 = blockIdx.z * 16;     // 16 batches per block
    const int w0 = wt * 8 + wg2 * 2;
    const bool val = !(wt == 3 && wg2 == 3);
    const int wwave = tid & ~63;        // wave-uniform lane-0 tid

    __shared__ float wgl[2][1216];      // [buf][ol*68 + w*8 + k] + k8 plane at 1088
    __shared__ float ffs[2][576];       // [buf][bb*36 + r*12 + cc]

    // ---- c-independent staging offsets (all in-bounds by construction) ----
    // weight element s = q*256 + tid -> (ol = s>>6 in 0..15, w = (s>>3)&7, k = s&7)
    int wq_off[4];
#pragma unroll
    for (int q = 0; q < 4; ++q) {
        int s = q * 256 + tid;          // 0..1023
        int ol = s >> 6, w = (s >> 3) & 7, k = s & 7;
        int colc = wt * 8 + w; if (colc > 29) colc = 29;   // edge clamp (garbage -> invalid threads only)
        wq_off[q] = (os * 16 + ol) * WSTRIDE_O + (h * WO_ + colc) * 9 + k;
    }
    int w8_off = 0;
    const bool k8on = (tid < 128);      // waves 0,1 stage the k=8 plane (128 floats)
    if (k8on) {
        int ol = tid >> 3, w = tid & 7;
        int colc = wt * 8 + w; if (colc > 29) colc = 29;
        w8_off = (os * 16 + ol) * WSTRIDE_O + (h * WO_ + colc) * 9 + 8;
    }
    const bool fon = (tid < 144);       // 144 lanes x 16B = 576 floats
    int f_off = 0;
    if (fon) {
        int s0 = 4 * tid;               // 0,4,...,572
        int bb = s0 / 36, rm = s0 % 36, r = rm / 12, cc0 = rm % 12;
        f_off = (b0 + bb) * FFB_ + (h + r) * W_ + wt * 8 + cc0;   // 16B-aligned
    }

    float acc[2][4];                     // [ww][j]
#pragma unroll
    for (int ww = 0; ww < 2; ++ww)
#pragma unroll
        for (int j = 0; j < 4; ++j) acc[ww][j] = 0.f;

    auto stage = [&](int c, int buf) {
        const float* wsrc = weight + c * WSTRIDE_C;
#pragma unroll
        for (int q = 0; q < 4; ++q)
            gload_lds4(wsrc + wq_off[q], &wgl[buf][(q * 4 + wave) * 68]);
        if (k8on) gload_lds4(wsrc + w8_off, &wgl[buf][1088 + (wave << 6)]);
        if (fon) {
            int g = f_off + c * FFC_;
            if (g > FFTOT_ - 4) g = FFTOT_ - 4;   // corner clamp (garbage slots only)
            gload_lds16(ff + g, &ffs[buf][4 * wwave]);
        }
    };

    auto compute_c = [&](int buf) {
        float wk[2][9];
#pragma unroll
        for (int ww = 0; ww < 2; ++ww) {
            const int w = wg2 * 2 + ww;
            const float* wp = &wgl[buf][og * 68 + w * 8];     // 272B group stride, 16B-aligned
            const float4 a = *reinterpret_cast<const float4*>(wp);
            const float4 b = *reinterpret_cast<const float4*>(wp + 4);
            wk[ww][0] = a.x; wk[ww][1] = a.y; wk[ww][2] = a.z; wk[ww][3] = a.w;
            wk[ww][4] = b.x; wk[ww][5] = b.y; wk[ww][6] = b.z; wk[ww][7] = b.w;
            wk[ww][8] = wgl[buf][1088 + og * 8 + w];
        }
#pragma unroll
        for (int j = 0; j < 4; ++j) {
            const int bb = bg * 4 + j;
            float fr[3][4];
#pragma unroll
            for (int r = 0; r < 3; ++r) {
                const float2 u = *reinterpret_cast<const float2*>(&ffs[buf][bb * 36 + r * 12 + wg2 * 2]);
                const float2 v = *reinterpret_cast<const float2*>(&ffs[buf][bb * 36 + r * 12 + wg2 * 2 + 2]);
                fr[r][0] = u.x; fr[r][1] = u.y; fr[r][2] = v.x; fr[r][3] = v.y;
            }
#pragma unroll
            for (int ww = 0; ww < 2; ++ww) {
                float a = acc[ww][j];
#pragma unroll
                for (int kh = 0; kh < 3; ++kh)
#pragma unroll
                    for (int kw = 0; kw < 3; ++kw) {
                        float prod = wk[ww][kh * 3 + kw] * fr[kh][ww + kw];
                        a = a + prod;      // no FMA, (c,kh,kw) order
                    }
                acc[ww][j] = a;
            }
        }
    };

    stage(0, 0);
    __syncthreads();
    for (int cs = 0; cs < CI_; cs += 2) {
        if (cs + 1 < CI_) stage(cs + 1, 1);   // prefetch overlaps compute
        compute_c(0);
        __syncthreads();
        if (cs + 2 < CI_) stage(cs + 2, 0);
        compute_c(1);
        __syncthreads();
    }

    // epilogue: bias, park conv values, exact f64 per-slot per-channel stats
    double s1 = 0.0, s2 = 0.0;
    const int o = os * 16 + og;
    if (val) {
        const int pidx = o * P_ + h * WO_ + w0;
        const float2 bi = *reinterpret_cast<const float2*>(conv_bias + pidx);
#pragma unroll
        for (int j = 0; j < 4; ++j) {
            const int b = b0 + bg * 4 + j;
            const size_t n = (size_t)b * CP_ + (size_t)pidx;
            float v0 = acc[0][j] + bi.x;         // f32, same as ref
            float v1 = acc[1][j] + bi.y;
            *reinterpret_cast<float2*>(outf + 3 * N_ + n) = make_float2(v0, v1);
            double d0 = (double)v0, d1 = (double)v1;
            s1 += d0; s2 += d0 * d0;
            s1 += d1; s2 += d1 * d1;
        }
    }
    // deterministic reduce over the 16 lanes (stride 4) sharing og
#pragma unroll
    for (int d = 4; d < 64; d <<= 1) {
        s1 += __shfl_xor(s1, d);
        s2 += __shfl_xor(s2, d);
    }
    if ((tid & 60) == 0) {               // wg2==0 && bg==0
        int blk = (blockIdx.z * 30 + blockIdx.y) * 4 + wt;   // 0..959 (same slots)
        part_sum  [blk * CO_ + o] = s1;
        part_sumsq[blk * CO_ + o] = s2;
    }
}

// ---------------------------------------------------------------------------
// Kernel 2: BN finalize — deterministic f64 reduction of partials (960
// slots), then f32 mean / inv_std per channel. UNCHANGED.
// ---------------------------------------------------------------------------
__global__ __launch_bounds__(256) void bn_finalize(
    const double* __restrict__ part_sum, const double* __restrict__ part_sumsq,
    float* __restrict__ Mb)
{
#pragma clang fp contract(off)
    const int o = blockIdx.x;
    const int tid = threadIdx.x;
    double s1 = 0.0, s2 = 0.0;
    for (int i = tid; i < NBLK_CONV; i += 256) {
        s1 += part_sum[i * CO_ + o];
        s2 += part_sumsq[i * CO_ + o];
    }
    __shared__ double r1[256], r2[256];
    r1[tid] = s1; r2[tid] = s2;
    __syncthreads();
    for (int s = 128; s > 0; s >>= 1) {
        if (tid < s) { r1[tid] += r1[tid + s]; r2[tid] += r2[tid + s]; }
        __syncthreads();
    }
    if (tid == 0) {
        const double cnt = (double)(B_ * (size_t)P_);
        double mean = r1[0] / cnt;
        float meanf = (float)mean;
        double md = (double)meanf;
        double var = r2[0] / cnt - 2.0 * md * (r1[0] / cnt) + md * md;
        float varf = (float)var;
        float invf = 1.0f / sqrtf(varf + 1e-5f);
        Mb[o]       = meanf;
        Mb[CO_ + o] = invf;
    }
}

// ---------------------------------------------------------------------------
// Kernel 3: fused recurrent-bmm + LIF. R7 VERBATIM (the 113-us champion's
// component): LDS spike tile, parity double-buffer, register prefetch,
// lgkmcnt(0)-only barrier; 1024 thr = 32 i x 32 p; XCD-grouped 1D grid
// (512 blocks): pt determines D&7, so the 16 b-blocks sharing a
// local_rec/tau p-slice land on one XCD's L2.
// ---------------------------------------------------------------------------
__global__ __launch_bounds__(1024) void lif_rec_kernel(
    float* __restrict__ outf, const float* __restrict__ local_rec,
    const float* __restrict__ tau_m, const float* __restrict__ tau_adp,
    const float* __restrict__ tau_a, const float* __restrict__ Mb,
    const float* __restrict__ gamma, const float* __restrict__ beta,
    const float* __restrict__ fb, const float* __restrict__ soma_t,
    const float* __restrict__ spk_t, const float* __restrict__ a_curr,
    const float* __restrict__ b_t)
{
#pragma clang fp contract(off)
    const int D    = blockIdx.x;
    const int pt8  = D & 7;
    const int rest = D >> 3;
    const int by   = rest & 15;
    const int ptq  = rest >> 4;          // 0..3
    const int pt   = ptq * 8 + pt8;      // 0..31
    if (pt >= 29) return;                // 29 p-tiles cover P_=900

    const int tid = threadIdx.x;
    const int pp  = tid & 31;
    const int i   = tid >> 5;            // channel 0..31
    const int p   = pt * 32 + pp;
    const bool pv = (p < P_);
    const int b0  = by * 8;

    float L[32];
    float meanf = 0.f, invf = 0.f, gm = 0.f, be = 0.f;
    float al = 0.f, rh = 0.f, et = 0.f;
    int rem = 0;
    if (pv) {
        const float4* lp = reinterpret_cast<const float4*>(local_rec + (size_t)p * (CO_ * CO_) + i * CO_);
#pragma unroll
        for (int q = 0; q < 8; ++q) {
            float4 v = lp[q];
            L[4 * q] = v.x; L[4 * q + 1] = v.y; L[4 * q + 2] = v.z; L[4 * q + 3] = v.w;
        }
        rem = i * P_ + p;
        meanf = Mb[i]; invf = Mb[CO_ + i];
        gm = gamma[i]; be = beta[i];
        // identical f32 ops to the original tau table: f32 divide then f32 exp
        al = expf(-0.5f / tau_m[rem]);
        rh = expf(-0.5f / tau_adp[rem]);
        et = expf(-0.5f / tau_a[rem]);
    }

    __shared__ float sp[2][CO_][32];

    // prologue: iteration-0 operands into registers
    size_t n = (size_t)b0 * CP_ + (size_t)rem;
    float sk_c = 0.f, cv_c = 0.f, bt_c = 0.f, ac_c = 0.f, fb_c = 0.f, so_c = 0.f;
    if (pv) {
        sk_c = spk_t[n]; cv_c = outf[3 * N_ + n]; bt_c = b_t[n];
        ac_c = a_curr[n]; fb_c = fb[n]; so_c = soma_t[n];
    }

#pragma unroll
    for (int bb = 0; bb < 8; ++bb) {
        const int cb = bb & 1;
        if (pv) sp[cb][i][pp] = sk_c;
        // prefetch next iteration BEFORE the barrier (stays in flight: the
        // raw barrier below drains lgkmcnt only, not vmcnt)
        float sk_n = 0.f, cv_n = 0.f, bt_n = 0.f, ac_n = 0.f, fb_n = 0.f, so_n = 0.f;
        if (bb + 1 < 8 && pv) {
            const size_t nn = n + (size_t)CP_;
            sk_n = spk_t[nn]; cv_n = outf[3 * N_ + nn]; bt_n = b_t[nn];
            ac_n = a_curr[nn]; fb_n = fb[nn]; so_n = soma_t[nn];
        }
        asm volatile("s_waitcnt lgkmcnt(0)\n\ts_barrier" ::: "memory");
        if (pv) {
            // rec: sequential f32 dot over j, no FMA (np einsum order)
            float rec = 0.f;
#pragma unroll
            for (int j = 0; j < CO_; ++j) {
                float prod = L[j] * sp[cb][j][pp];
                rec = rec + prod;
            }

            // BN exactly as reference
            float t  = cv_c - meanf;
            float x  = t * invf;
            float xg = x * gm;
            float cx = xg + be;
            cx = cx + rec;

            // b_new = rho*b_t + (1-rho)*spk
            float rb  = rh * bt_c;
            float omr = 1.0f - rh;
            float os  = omr * sk_c;
            float bn  = rb + os;
            // new_thre = 0.1 + 1.8*b_new
            float tb = 1.8f * bn;
            float th = 0.1f + tb;
            // a_new = eta*a_curr + fb
            float ea = et * ac_c;
            float an = ea + fb_c;
            // sigmoid
            float sg = 1.0f / (1.0f + expf(-an));
            // soma_new = alpha*soma + (sig-0.5) + cx - thre*spk  (left-to-right)
            float as = al * so_c;
            float s5 = sg - 0.5f;
            float u1 = as + s5;
            float u2 = u1 + cx;
            float ts = th * sk_c;
            float sn = u2 - ts;

            outf[n]          = sn;
            outf[N_ + n]     = ((sn - th) > 0.0f) ? 1.f : 0.f;
            outf[2 * N_ + n] = an;
            outf[3 * N_ + n] = bn;                                // overwrites conv
        }
        sk_c = sk_n; cv_c = cv_n; bt_c = bt_n; ac_c = ac_n; fb_c = fb_n; so_c = so_n;
        n += (size_t)CP_;
    }
}

extern "C" void kernel_launch(void* const* d_in, const int* in_sizes, int n_in,
                              void* d_out, int out_size, void* d_ws, size_t ws_size,
                              hipStream_t stream)
{
    const float* ff        = (const float*)d_in[0];
    const float* fb        = (const float*)d_in[1];
    const float* soma_t    = (const float*)d_in[2];
    const float* spk_t     = (const float*)d_in[3];
    const float* a_curr    = (const float*)d_in[4];
    const float* b_t       = (const float*)d_in[5];
    const float* weight    = (const float*)d_in[6];
    const float* conv_bias = (const float*)d_in[7];
    const float* local_rec = (const float*)d_in[8];
    const float* gamma     = (const float*)d_in[9];
    const float* beta      = (const float*)d_in[10];
    const float* tau_m     = (const float*)d_in[11];
    const float* tau_adp   = (const float*)d_in[12];
    const float* tau_a     = (const float*)d_in[13];

    // ws: f64 partials then Mb (~0.5 MB total)
    double* part_sum = (double*)d_ws;                       // NBLK_CONV*CO_
    double* part_sq  = part_sum + (size_t)NBLK_CONV * CO_;  // NBLK_CONV*CO_
    float*  Mb       = (float*)(part_sq + (size_t)NBLK_CONV * CO_);  // 64

    float* outf = (float*)d_out;

    conv_kernel<<<dim3(8, 30, 8), 256, 0, stream>>>(
        ff, weight, conv_bias, outf, part_sum, part_sq);
    bn_finalize<<<dim3(CO_), 256, 0, stream>>>(part_sum, part_sq, Mb);
    lif_rec_kernel<<<dim3(512), 1024, 0, stream>>>(
        outf, local_rec, tau_m, tau_adp, tau_a, Mb, gamma, beta,
        fb, soma_t, spk_t, a_curr, b_t);
}